// Round 1
// baseline (1472.951 us; speedup 1.0000x reference)
//
#include <hip/hip_runtime.h>
#include <hip/hip_bf16.h>
#include <math.h>

#define B_SZ 2
#define T_LEN 1024
#define DMODEL 1024
#define DINNER 2048
#define DSTATE 16
#define DCONV 4
#define DTRANK 64

__device__ __forceinline__ float sigmoid_f(float v) { return 1.f / (1.f + __expf(-v)); }

// C[M,N] = A[M,K] * B[N,K]^T  (both row-major, NT).  EPI: 0=none, 1=softplus(v+bias[n])
template<int EPI>
__global__ __launch_bounds__(256) void gemm_nt(const float* __restrict__ A, int lda,
                                               const float* __restrict__ Bm, int ldb,
                                               float* __restrict__ C, int ldc,
                                               int M, int N, int K,
                                               const float* __restrict__ bias)
{
    // [k][m] layout, padded second dim to 68 -> <=2-way bank conflicts (free)
    __shared__ float As[16][68];
    __shared__ float Bs[16][68];
    const int tx = threadIdx.x & 15;
    const int ty = threadIdx.x >> 4;
    const int m0 = blockIdx.y * 64;
    const int n0 = blockIdx.x * 64;
    // loader mapping: each thread loads 4 consecutive k (float4)
    const int lr = threadIdx.x >> 2;          // row in tile 0..63
    const int lc = (threadIdx.x & 3) * 4;     // k offset 0,4,8,12

    float acc[4][4] = {};

    for (int k0 = 0; k0 < K; k0 += 16) {
        // A tile
        {
            int m = m0 + lr;
            float4 v = make_float4(0.f, 0.f, 0.f, 0.f);
            if (m < M) v = *reinterpret_cast<const float4*>(&A[(size_t)m * lda + k0 + lc]);
            As[lc + 0][lr] = v.x; As[lc + 1][lr] = v.y;
            As[lc + 2][lr] = v.z; As[lc + 3][lr] = v.w;
        }
        // B tile
        {
            int n = n0 + lr;
            float4 v = make_float4(0.f, 0.f, 0.f, 0.f);
            if (n < N) v = *reinterpret_cast<const float4*>(&Bm[(size_t)n * ldb + k0 + lc]);
            Bs[lc + 0][lr] = v.x; Bs[lc + 1][lr] = v.y;
            Bs[lc + 2][lr] = v.z; Bs[lc + 3][lr] = v.w;
        }
        __syncthreads();
        #pragma unroll
        for (int kk = 0; kk < 16; ++kk) {
            float av[4], bv[4];
            #pragma unroll
            for (int i = 0; i < 4; ++i) av[i] = As[kk][ty + 16 * i];
            #pragma unroll
            for (int j = 0; j < 4; ++j) bv[j] = Bs[kk][tx + 16 * j];
            #pragma unroll
            for (int i = 0; i < 4; ++i)
                #pragma unroll
                for (int j = 0; j < 4; ++j)
                    acc[i][j] = fmaf(av[i], bv[j], acc[i][j]);
        }
        __syncthreads();
    }

    #pragma unroll
    for (int i = 0; i < 4; ++i) {
        int m = m0 + ty + 16 * i;
        if (m >= M) continue;
        #pragma unroll
        for (int j = 0; j < 4; ++j) {
            int n = n0 + tx + 16 * j;
            if (n >= N) continue;
            float v = acc[i][j];
            if (EPI == 1) {
                v += bias[n];
                v = (v > 20.f) ? v : log1pf(__expf(v));
            }
            C[(size_t)m * ldc + n] = v;
        }
    }
}

// causal depthwise conv1d over t (k=4, left-pad 3) + bias + SiLU
// reads x-branch (first DINNER cols of xz), writes xs
__global__ __launch_bounds__(256) void conv_silu_kernel(const float* __restrict__ xz,
                                                        const float* __restrict__ cw,
                                                        const float* __restrict__ cb,
                                                        float* __restrict__ xs)
{
    int tid = blockIdx.x * blockDim.x + threadIdx.x;  // b*T*DINNER + t*DINNER + d
    int d = tid & (DINNER - 1);
    int t = (tid >> 11) & (T_LEN - 1);
    int b = tid >> 21;
    float acc = cb[d];
    #pragma unroll
    for (int j = 0; j < DCONV; ++j) {
        int tt = t - (DCONV - 1) + j;
        if (tt >= 0)
            acc = fmaf(xz[((size_t)(b * T_LEN + tt)) * (2 * DINNER) + d], cw[d * DCONV + j], acc);
    }
    xs[tid] = acc * sigmoid_f(acc);
}

// selective scan: one wave = 4 channels x 16 states; fused epilogue
// y = (scan_y + xs*D) * silu(z).   NOTE: y may alias dt (read-before-write per t).
__global__ __launch_bounds__(256) void scan_kernel(const float* dt,
                                                   const float* __restrict__ xs,
                                                   const float* __restrict__ xdbl,
                                                   const float* __restrict__ A_log,
                                                   const float* __restrict__ Dp,
                                                   const float* __restrict__ xz,
                                                   float* y)
{
    const int wave = (blockIdx.x * blockDim.x + threadIdx.x) >> 6;
    const int lane = threadIdx.x & 63;
    const int s = lane & 15;
    const int di = lane >> 4;
    const int b = wave >> 9;                 // 512 waves per batch
    const int d = ((wave & 511) << 2) + di;

    const float a = -__expf(A_log[d * DSTATE + s]);
    const float Dv = Dp[d];

    float h = 0.f;
    for (int t = 0; t < T_LEN; ++t) {
        const size_t row = (size_t)(b * T_LEN + t);
        const float dtv = dt[row * DINNER + d];
        const float xv  = xs[row * DINNER + d];
        const float Bv  = xdbl[row * 96 + DTRANK + s];
        const float Cv  = xdbl[row * 96 + DTRANK + DSTATE + s];
        const float dA = __expf(dtv * a);
        h = dA * h + (dtv * xv) * Bv;
        float p = h * Cv;
        p += __shfl_xor(p, 1, 64);
        p += __shfl_xor(p, 2, 64);
        p += __shfl_xor(p, 4, 64);
        p += __shfl_xor(p, 8, 64);
        if (s == 0) {
            const float zv = xz[row * (2 * DINNER) + DINNER + d];
            const float g = zv * sigmoid_f(zv);
            y[row * DINNER + d] = (p + xv * Dv) * g;
        }
    }
}

extern "C" void kernel_launch(void* const* d_in, const int* in_sizes, int n_in,
                              void* d_out, int out_size, void* d_ws, size_t ws_size,
                              hipStream_t stream) {
    const float* x         = (const float*)d_in[0];
    const float* in_proj_w = (const float*)d_in[1];
    const float* conv_w    = (const float*)d_in[2];
    const float* conv_b    = (const float*)d_in[3];
    const float* x_proj_w  = (const float*)d_in[4];
    const float* dt_proj_w = (const float*)d_in[5];
    const float* dt_proj_b = (const float*)d_in[6];
    const float* A_log     = (const float*)d_in[7];
    const float* D_param   = (const float*)d_in[8];
    const float* out_proj_w= (const float*)d_in[9];
    float* out = (float*)d_out;

    float* ws   = (float*)d_ws;
    float* xz   = ws;                                            // B*T*4096
    float* xs   = xz + (size_t)B_SZ * T_LEN * 2 * DINNER;        // B*T*2048
    float* xdbl = xs + (size_t)B_SZ * T_LEN * DINNER;            // B*T*96
    float* dtb  = xdbl + (size_t)B_SZ * T_LEN * (DTRANK + 2 * DSTATE); // B*T*2048
    float* y    = dtb;  // alias: scan reads dt[t][d] before writing y[t][d] in same wave-iter

    const int M = B_SZ * T_LEN;  // 2048
    dim3 blk(256);

    // 1. in_proj: xz = x @ in_proj_w^T   (2048 x 4096, K=1024)
    gemm_nt<0><<<dim3((2 * DINNER) / 64, M / 64), blk, 0, stream>>>(
        x, DMODEL, in_proj_w, DMODEL, xz, 2 * DINNER, M, 2 * DINNER, DMODEL, nullptr);

    // 2. causal conv + SiLU -> xs
    conv_silu_kernel<<<(B_SZ * T_LEN * DINNER) / 256, blk, 0, stream>>>(xz, conv_w, conv_b, xs);

    // 3. x_proj: xdbl = xs @ x_proj_w^T  (2048 x 96, K=2048)
    gemm_nt<0><<<dim3(2, M / 64), blk, 0, stream>>>(
        xs, DINNER, x_proj_w, DINNER, xdbl, 96, M, 96, DINNER, nullptr);

    // 4. dt_proj + softplus: dtb = softplus(xdbl[:, :64] @ dt_proj_w^T + b)  (2048 x 2048, K=64)
    gemm_nt<1><<<dim3(DINNER / 64, M / 64), blk, 0, stream>>>(
        xdbl, 96, dt_proj_w, DTRANK, dtb, DINNER, M, DINNER, DTRANK, dt_proj_b);

    // 5. selective scan + gated epilogue -> y (aliases dtb)
    scan_kernel<<<256, blk, 0, stream>>>(dtb, xs, xdbl, A_log, D_param, xz, y);

    // 6. out_proj: out = y @ out_proj_w^T  (2048 x 1024, K=2048)
    gemm_nt<0><<<dim3(DMODEL / 64, M / 64), blk, 0, stream>>>(
        y, DINNER, out_proj_w, DINNER, out, DMODEL, M, DMODEL, DINNER, nullptr);
}

// Round 3
// 876.391 us; speedup vs baseline: 1.6807x; 1.6807x over previous
//
#include <hip/hip_runtime.h>
#include <hip/hip_bf16.h>
#include <math.h>

#define B_SZ 2
#define T_LEN 1024
#define DMODEL 1024
#define DINNER 2048
#define DSTATE 16
#define DCONV 4
#define DTRANK 64
#define MTOK (B_SZ * T_LEN)   // 2048 tokens

__device__ __forceinline__ float sigmoid_f(float v) { return 1.f / (1.f + __expf(-v)); }

// C[M,N] = A * B^T.  A: [M][K] (TA=0) or [K][M] (TA=1, time-major). B: [N][K].
// EPI: 0 = none, 2 = softplus(v + bias[row m])
template<int EPI, int TA>
__global__ __launch_bounds__(256) void gemm_nt(const float* __restrict__ A, int lda,
                                               const float* __restrict__ Bm, int ldb,
                                               float* __restrict__ C, int ldc,
                                               int M, int N, int K,
                                               const float* __restrict__ bias)
{
    __shared__ float As[16][68];   // [k][m], pad -> <=2-way conflicts (free)
    __shared__ float Bs[16][68];   // [k][n]
    const int tx = threadIdx.x & 15;
    const int ty = threadIdx.x >> 4;
    const int m0 = blockIdx.y * 64;
    const int n0 = blockIdx.x * 64;
    const int lr = threadIdx.x >> 2;          // tile row 0..63
    const int lc = (threadIdx.x & 3) * 4;     // k offset 0,4,8,12
    const int kk16 = threadIdx.x >> 4;        // TA: k row 0..15
    const int mc16 = (threadIdx.x & 15) * 4;  // TA: m offset 0..60

    float acc[4][4] = {};

    for (int k0 = 0; k0 < K; k0 += 16) {
        if (TA) {
            // A is [K][M]: load 16 k-rows x 64 m, coalesced along m
            float4 v = *reinterpret_cast<const float4*>(&A[(size_t)(k0 + kk16) * lda + m0 + mc16]);
            As[kk16][mc16 + 0] = v.x; As[kk16][mc16 + 1] = v.y;
            As[kk16][mc16 + 2] = v.z; As[kk16][mc16 + 3] = v.w;
        } else {
            int m = m0 + lr;
            float4 v = make_float4(0.f, 0.f, 0.f, 0.f);
            if (m < M) v = *reinterpret_cast<const float4*>(&A[(size_t)m * lda + k0 + lc]);
            As[lc + 0][lr] = v.x; As[lc + 1][lr] = v.y;
            As[lc + 2][lr] = v.z; As[lc + 3][lr] = v.w;
        }
        {
            int n = n0 + lr;
            float4 v = make_float4(0.f, 0.f, 0.f, 0.f);
            if (n < N) v = *reinterpret_cast<const float4*>(&Bm[(size_t)n * ldb + k0 + lc]);
            Bs[lc + 0][lr] = v.x; Bs[lc + 1][lr] = v.y;
            Bs[lc + 2][lr] = v.z; Bs[lc + 3][lr] = v.w;
        }
        __syncthreads();
        #pragma unroll
        for (int kk = 0; kk < 16; ++kk) {
            float av[4], bv[4];
            #pragma unroll
            for (int i = 0; i < 4; ++i) av[i] = As[kk][ty + 16 * i];
            #pragma unroll
            for (int j = 0; j < 4; ++j) bv[j] = Bs[kk][tx + 16 * j];
            #pragma unroll
            for (int i = 0; i < 4; ++i)
                #pragma unroll
                for (int j = 0; j < 4; ++j)
                    acc[i][j] = fmaf(av[i], bv[j], acc[i][j]);
        }
        __syncthreads();
    }

    #pragma unroll
    for (int i = 0; i < 4; ++i) {
        int m = m0 + ty + 16 * i;
        if (m >= M) continue;
        float rb = (EPI == 2) ? bias[m] : 0.f;
        #pragma unroll
        for (int j = 0; j < 4; ++j) {
            int n = n0 + tx + 16 * j;
            if (n >= N) continue;
            float v = acc[i][j];
            if (EPI == 2) {
                v += rb;
                v = (v > 20.f) ? v : log1pf(__expf(v));
            }
            C[(size_t)m * ldc + n] = v;
        }
    }
}

// causal depthwise conv (k=4, left pad 3) + bias + SiLU, output TRANSPOSED:
// xsT[d][m] from xz[m][d] (x-branch = first DINNER cols). Tile: 64 d x 16 t.
__global__ __launch_bounds__(256) void conv_silu_t_kernel(const float* __restrict__ xz,
                                                          const float* __restrict__ cw,
                                                          const float* __restrict__ cb,
                                                          float* __restrict__ xsT)
{
    __shared__ float s_in[19][64];
    __shared__ float s_out[64][17];
    const int m0 = blockIdx.x * 16;
    const int d0 = blockIdx.y * 64;
    const int tid = threadIdx.x;
    const int tb = m0 & (T_LEN - 1);   // t offset of tile within its batch

    for (int idx = tid; idx < 19 * 64; idx += 256) {
        int r = idx >> 6, dd = idx & 63;
        float v = 0.f;
        if (tb + r - 3 >= 0)
            v = xz[(size_t)(m0 + r - 3) * (2 * DINNER) + d0 + dd];
        s_in[r][dd] = v;
    }
    __syncthreads();

    const int dl = tid & 63;
    const int tg = tid >> 6;           // uniform per wave
    const int d = d0 + dl;
    const float4 w = *reinterpret_cast<const float4*>(&cw[d * DCONV]);
    const float bia = cb[d];
    #pragma unroll
    for (int j = 0; j < 4; ++j) {
        int tt = tg * 4 + j;
        float acc = bia;
        acc = fmaf(s_in[tt + 0][dl], w.x, acc);
        acc = fmaf(s_in[tt + 1][dl], w.y, acc);
        acc = fmaf(s_in[tt + 2][dl], w.z, acc);
        acc = fmaf(s_in[tt + 3][dl], w.w, acc);
        s_out[dl][tt] = acc * sigmoid_f(acc);
    }
    __syncthreads();

    const int dd2 = tid >> 2;
    const int tc = (tid & 3) * 4;
    float4 o;
    o.x = s_out[dd2][tc + 0]; o.y = s_out[dd2][tc + 1];
    o.z = s_out[dd2][tc + 2]; o.w = s_out[dd2][tc + 3];
    *reinterpret_cast<float4*>(&xsT[(size_t)(d0 + dd2) * MTOK + m0 + tc]) = o;
}

// dst[r][c] = src[c][r]; dst R x C (row-major ld_dst), src with leading dim ld_src.
// grid = (C/32, R/32) exact.
__global__ __launch_bounds__(256) void transpose32(const float* __restrict__ src, int ld_src,
                                                   float* __restrict__ dst, int ld_dst)
{
    __shared__ float t[32][33];
    const int c0 = blockIdx.x * 32;
    const int r0 = blockIdx.y * 32;
    const int tx = threadIdx.x & 31;
    const int ty = threadIdx.x >> 5;   // 0..7
    #pragma unroll
    for (int rep = 0; rep < 4; ++rep) {
        int row = ty + rep * 8;
        t[row][tx] = src[(size_t)(c0 + row) * ld_src + r0 + tx];
    }
    __syncthreads();
    #pragma unroll
    for (int rep = 0; rep < 4; ++rep) {
        int row = ty + rep * 8;
        dst[(size_t)(r0 + row) * ld_dst + c0 + tx] = t[tx][row];
    }
}

// selective scan, time-major float4 (4 timesteps per load), register prefetch.
// wave = 4 channels x 16 states; y = (scan_y + xs*D) * silu(z), stored transposed.
__global__ __launch_bounds__(256) void scan_kernel(const float* __restrict__ dtT,
                                                   const float* __restrict__ xsT,
                                                   const float* __restrict__ bcT,
                                                   const float* __restrict__ zT,
                                                   const float* __restrict__ A_log,
                                                   const float* __restrict__ Dp,
                                                   float* __restrict__ yT)
{
    const int wave = (blockIdx.x * blockDim.x + threadIdx.x) >> 6;
    const int lane = threadIdx.x & 63;
    const int s = lane & 15;
    const int di = lane >> 4;
    const int b = wave >> 9;                  // 512 waves per batch
    const int d = ((wave & 511) << 2) + di;

    const float a = -__expf(A_log[d * DSTATE + s]);
    const float Dv = Dp[d];

    const float4* dtp = reinterpret_cast<const float4*>(dtT + (size_t)d * MTOK + b * T_LEN);
    const float4* xsp = reinterpret_cast<const float4*>(xsT + (size_t)d * MTOK + b * T_LEN);
    const float4* Bp  = reinterpret_cast<const float4*>(bcT + (size_t)s * MTOK + b * T_LEN);
    const float4* Cp  = reinterpret_cast<const float4*>(bcT + (size_t)(DSTATE + s) * MTOK + b * T_LEN);
    const float4* zp  = reinterpret_cast<const float4*>(zT + (size_t)d * MTOK + b * T_LEN);
    float4* yp = reinterpret_cast<float4*>(yT + (size_t)d * MTOK + b * T_LEN);

    float4 dt0 = dtp[0], xs0 = xsp[0], B0 = Bp[0], C0 = Cp[0], z0 = zp[0];
    float h = 0.f;

    for (int q = 0; q < T_LEN / 4; ++q) {
        const float4 dtv = dt0, xv = xs0, Bv = B0, Cv = C0, zv = z0;
        if (q < T_LEN / 4 - 1) {
            dt0 = dtp[q + 1]; xs0 = xsp[q + 1]; B0 = Bp[q + 1];
            C0 = Cp[q + 1];   z0 = zp[q + 1];
        }
        float4 yv;
        #define SCAN_STEP(c)                                                    \
        {                                                                       \
            const float dtj = dtv.c;                                            \
            const float dA = __expf(dtj * a);                                   \
            h = fmaf(dA, h, dtj * xv.c * Bv.c);                                 \
            float p = h * Cv.c;                                                 \
            p += __shfl_xor(p, 1, 64);                                          \
            p += __shfl_xor(p, 2, 64);                                          \
            p += __shfl_xor(p, 4, 64);                                          \
            p += __shfl_xor(p, 8, 64);                                          \
            yv.c = p;                                                           \
        }
        SCAN_STEP(x) SCAN_STEP(y) SCAN_STEP(z) SCAN_STEP(w)
        #undef SCAN_STEP
        if (s == 0) {
            float4 o;
            #define GATE(c) { float g = zv.c * sigmoid_f(zv.c); o.c = (yv.c + xv.c * Dv) * g; }
            GATE(x) GATE(y) GATE(z) GATE(w)
            #undef GATE
            yp[q] = o;
        }
    }
}

extern "C" void kernel_launch(void* const* d_in, const int* in_sizes, int n_in,
                              void* d_out, int out_size, void* d_ws, size_t ws_size,
                              hipStream_t stream) {
    const float* x         = (const float*)d_in[0];
    const float* in_proj_w = (const float*)d_in[1];
    const float* conv_w    = (const float*)d_in[2];
    const float* conv_b    = (const float*)d_in[3];
    const float* x_proj_w  = (const float*)d_in[4];
    const float* dt_proj_w = (const float*)d_in[5];
    const float* dt_proj_b = (const float*)d_in[6];
    const float* A_log     = (const float*)d_in[7];
    const float* D_param   = (const float*)d_in[8];
    const float* out_proj_w= (const float*)d_in[9];
    float* out = (float*)d_out;

    // ws layout (floats):
    // [0, 8M)      xz (tokens x 4096); after xz is dead: dtT = [0,4M), yT = [4M,8M)
    // [8M, 12M)    xsT
    // [12M, ...)   xdbl (2048x96), bcT (32x2048), zT (2048x2048)
    float* ws   = (float*)d_ws;
    const size_t M4 = (size_t)4 * 1024 * 1024;
    float* xz   = ws;
    float* dtT  = ws;            // aliases xz rows 0..1023 (xz dead by then)
    float* yT   = ws + M4;       // aliases xz rows 1024..2047
    float* xsT  = ws + 2 * M4;
    float* xdbl = ws + 3 * M4;
    float* bcT  = xdbl + (size_t)MTOK * 96;
    float* zT   = bcT + (size_t)2 * DSTATE * MTOK;

    dim3 blk(256);

    // 1. in_proj: xz[m][4096] = x @ in_proj_w^T
    gemm_nt<0, 0><<<dim3(64, 32), blk, 0, stream>>>(
        x, DMODEL, in_proj_w, DMODEL, xz, 2 * DINNER, MTOK, 2 * DINNER, DMODEL, nullptr);

    // 2. causal conv + SiLU -> xsT[d][m]
    conv_silu_t_kernel<<<dim3(MTOK / 16, DINNER / 64), blk, 0, stream>>>(xz, conv_w, conv_b, xsT);

    // 3. zT[d][m] = xz[m][2048+d]
    transpose32<<<dim3(MTOK / 32, DINNER / 32), blk, 0, stream>>>(xz + DINNER, 2 * DINNER, zT, MTOK);

    // 4. x_proj: xdbl[m][96] = xs @ x_proj_w^T  (A time-major)
    gemm_nt<0, 1><<<dim3(2, 32), blk, 0, stream>>>(
        xsT, MTOK, x_proj_w, DINNER, xdbl, 96, MTOK, DTRANK + 2 * DSTATE, DINNER, nullptr);

    // 5. dt_proj transposed-out: dtT[e][m] = softplus(W_dt @ dt_in^T + b[e])
    gemm_nt<2, 0><<<dim3(32, 32), blk, 0, stream>>>(
        dt_proj_w, DTRANK, xdbl, 96, dtT, MTOK, DINNER, MTOK, DTRANK, dt_proj_b);

    // 6. bcT[0:16][m] = B^T, bcT[16:32][m] = C^T
    transpose32<<<dim3(MTOK / 32, 1), blk, 0, stream>>>(xdbl + DTRANK, 96, bcT, MTOK);

    // 7. selective scan + gated epilogue -> yT[d][m]
    scan_kernel<<<dim3(256), blk, 0, stream>>>(dtT, xsT, bcT, zT, A_log, D_param, yT);

    // 8. out_proj: out[m][1024] = y @ out_proj_w^T  (A time-major)
    gemm_nt<0, 1><<<dim3(16, 32), blk, 0, stream>>>(
        yT, MTOK, out_proj_w, DINNER, out, DMODEL, MTOK, DMODEL, DINNER, nullptr);
}

// Round 4
// 570.172 us; speedup vs baseline: 2.5833x; 1.5371x over previous
//
#include <hip/hip_runtime.h>
#include <hip/hip_bf16.h>
#include <math.h>

#define B_SZ 2
#define T_LEN 1024
#define DMODEL 1024
#define DINNER 2048
#define DSTATE 16
#define DCONV 4
#define DTRANK 64
#define MTOK (B_SZ * T_LEN)   // 2048 tokens

typedef __bf16 bf16x4 __attribute__((ext_vector_type(4)));
typedef __bf16 bf16x8 __attribute__((ext_vector_type(8)));
typedef float  f32x4  __attribute__((ext_vector_type(4)));

__device__ __forceinline__ float sigmoid_f(float v) { return 1.f / (1.f + __expf(-v)); }

// ---------------------------------------------------------------------------
// bf16 MFMA GEMM: C[M,N] = A[M,K] * B[N,K]^T, fp32 in/out (convert to bf16
// during LDS staging), fp32 accumulate. M,N % 128 == 0, K % 64 == 0.
// 128x128 tile, 4 waves (2x2 of 64x64), K_STEP=64, v_mfma_f32_16x16x32_bf16.
// LDS rows padded to 72 halfs (144 B) -> 16B-aligned rows, <=2-way conflicts.
// ---------------------------------------------------------------------------
#define LDK 72

__global__ __launch_bounds__(256) void mfma_gemm_nt(const float* __restrict__ A, int lda,
                                                    const float* __restrict__ Bm, int ldb,
                                                    float* __restrict__ C, int ldc,
                                                    int K)
{
    __shared__ __bf16 As[128 * LDK];
    __shared__ __bf16 Bs[128 * LDK];
    const int tid  = threadIdx.x;
    const int lane = tid & 63;
    const int w    = tid >> 6;
    const int wr   = w >> 1, wc = w & 1;
    const int m0   = blockIdx.y * 128, n0 = blockIdx.x * 128;

    const int srow  = tid >> 1;            // staging row 0..127
    const int skoff = (tid & 1) * 32;      // float offset 0 / 32

    f32x4 acc[4][4];
    #pragma unroll
    for (int i = 0; i < 4; ++i)
        #pragma unroll
        for (int j = 0; j < 4; ++j) {
            f32x4 z = {0.f, 0.f, 0.f, 0.f};
            acc[i][j] = z;
        }

    const int fr = lane & 15;              // fragment row within 16
    const int kq = (lane >> 4) * 8;        // k sub-offset within 32

    for (int k0 = 0; k0 < K; k0 += 64) {
        // ---- stage A,B tiles (fp32 -> bf16) ----
        const float* gA = A  + (size_t)(m0 + srow) * lda + k0 + skoff;
        const float* gB = Bm + (size_t)(n0 + srow) * ldb + k0 + skoff;
        __bf16* sA = As + srow * LDK + skoff;
        __bf16* sB = Bs + srow * LDK + skoff;
        #pragma unroll
        for (int p = 0; p < 8; ++p) {
            float4 va = *reinterpret_cast<const float4*>(gA + 4 * p);
            bf16x4 ba = {(__bf16)va.x, (__bf16)va.y, (__bf16)va.z, (__bf16)va.w};
            *reinterpret_cast<bf16x4*>(sA + 4 * p) = ba;
            float4 vb = *reinterpret_cast<const float4*>(gB + 4 * p);
            bf16x4 bb = {(__bf16)vb.x, (__bf16)vb.y, (__bf16)vb.z, (__bf16)vb.w};
            *reinterpret_cast<bf16x4*>(sB + 4 * p) = bb;
        }
        __syncthreads();

        // ---- fragments + MFMA ----
        bf16x8 af[4][2], bf[4][2];
        #pragma unroll
        for (int i = 0; i < 4; ++i) {
            const __bf16* pa = As + (wr * 64 + i * 16 + fr) * LDK + kq;
            af[i][0] = *reinterpret_cast<const bf16x8*>(pa);
            af[i][1] = *reinterpret_cast<const bf16x8*>(pa + 32);
        }
        #pragma unroll
        for (int j = 0; j < 4; ++j) {
            const __bf16* pb = Bs + (wc * 64 + j * 16 + fr) * LDK + kq;
            bf[j][0] = *reinterpret_cast<const bf16x8*>(pb);
            bf[j][1] = *reinterpret_cast<const bf16x8*>(pb + 32);
        }
        #pragma unroll
        for (int i = 0; i < 4; ++i)
            #pragma unroll
            for (int j = 0; j < 4; ++j) {
                acc[i][j] = __builtin_amdgcn_mfma_f32_16x16x32_bf16(af[i][0], bf[j][0], acc[i][j], 0, 0, 0);
                acc[i][j] = __builtin_amdgcn_mfma_f32_16x16x32_bf16(af[i][1], bf[j][1], acc[i][j], 0, 0, 0);
            }
        __syncthreads();
    }

    // ---- C write: lane l -> col = l&15, row = (l>>4)*4 + r ----
    const int crow = (lane >> 4) * 4;
    const int ccol = lane & 15;
    #pragma unroll
    for (int i = 0; i < 4; ++i)
        #pragma unroll
        for (int j = 0; j < 4; ++j) {
            float* cp = C + (size_t)(m0 + wr * 64 + i * 16 + crow) * ldc
                          + n0 + wc * 64 + j * 16 + ccol;
            cp[0 * ldc] = acc[i][j][0];
            cp[1 * ldc] = acc[i][j][1];
            cp[2 * ldc] = acc[i][j][2];
            cp[3 * ldc] = acc[i][j][3];
        }
}

// ---------------------------------------------------------------------------
// fp32 vector GEMM (kept for the small / precision-sensitive projections)
// C[M,N] = A * B^T.  A: [M][K] (TA=0) or [K][M] (TA=1). B: [N][K].
// EPI: 0 = none, 2 = softplus(v + bias[row m])
// ---------------------------------------------------------------------------
template<int EPI, int TA>
__global__ __launch_bounds__(256) void gemm_nt(const float* __restrict__ A, int lda,
                                               const float* __restrict__ Bm, int ldb,
                                               float* __restrict__ C, int ldc,
                                               int M, int N, int K,
                                               const float* __restrict__ bias)
{
    __shared__ float As[16][68];
    __shared__ float Bs[16][68];
    const int tx = threadIdx.x & 15;
    const int ty = threadIdx.x >> 4;
    const int m0 = blockIdx.y * 64;
    const int n0 = blockIdx.x * 64;
    const int lr = threadIdx.x >> 2;
    const int lc = (threadIdx.x & 3) * 4;
    const int kk16 = threadIdx.x >> 4;
    const int mc16 = (threadIdx.x & 15) * 4;

    float acc[4][4] = {};

    for (int k0 = 0; k0 < K; k0 += 16) {
        if (TA) {
            float4 v = *reinterpret_cast<const float4*>(&A[(size_t)(k0 + kk16) * lda + m0 + mc16]);
            As[kk16][mc16 + 0] = v.x; As[kk16][mc16 + 1] = v.y;
            As[kk16][mc16 + 2] = v.z; As[kk16][mc16 + 3] = v.w;
        } else {
            int m = m0 + lr;
            float4 v = make_float4(0.f, 0.f, 0.f, 0.f);
            if (m < M) v = *reinterpret_cast<const float4*>(&A[(size_t)m * lda + k0 + lc]);
            As[lc + 0][lr] = v.x; As[lc + 1][lr] = v.y;
            As[lc + 2][lr] = v.z; As[lc + 3][lr] = v.w;
        }
        {
            int n = n0 + lr;
            float4 v = make_float4(0.f, 0.f, 0.f, 0.f);
            if (n < N) v = *reinterpret_cast<const float4*>(&Bm[(size_t)n * ldb + k0 + lc]);
            Bs[lc + 0][lr] = v.x; Bs[lc + 1][lr] = v.y;
            Bs[lc + 2][lr] = v.z; Bs[lc + 3][lr] = v.w;
        }
        __syncthreads();
        #pragma unroll
        for (int kk = 0; kk < 16; ++kk) {
            float av[4], bv[4];
            #pragma unroll
            for (int i = 0; i < 4; ++i) av[i] = As[kk][ty + 16 * i];
            #pragma unroll
            for (int j = 0; j < 4; ++j) bv[j] = Bs[kk][tx + 16 * j];
            #pragma unroll
            for (int i = 0; i < 4; ++i)
                #pragma unroll
                for (int j = 0; j < 4; ++j)
                    acc[i][j] = fmaf(av[i], bv[j], acc[i][j]);
        }
        __syncthreads();
    }

    #pragma unroll
    for (int i = 0; i < 4; ++i) {
        int m = m0 + ty + 16 * i;
        if (m >= M) continue;
        float rb = (EPI == 2) ? bias[m] : 0.f;
        #pragma unroll
        for (int j = 0; j < 4; ++j) {
            int n = n0 + tx + 16 * j;
            if (n >= N) continue;
            float v = acc[i][j];
            if (EPI == 2) {
                v += rb;
                v = (v > 20.f) ? v : log1pf(__expf(v));
            }
            C[(size_t)m * ldc + n] = v;
        }
    }
}

// causal depthwise conv (k=4, left pad 3) + bias + SiLU, output TRANSPOSED
__global__ __launch_bounds__(256) void conv_silu_t_kernel(const float* __restrict__ xz,
                                                          const float* __restrict__ cw,
                                                          const float* __restrict__ cb,
                                                          float* __restrict__ xsT)
{
    __shared__ float s_in[19][64];
    __shared__ float s_out[64][17];
    const int m0 = blockIdx.x * 16;
    const int d0 = blockIdx.y * 64;
    const int tid = threadIdx.x;
    const int tb = m0 & (T_LEN - 1);

    for (int idx = tid; idx < 19 * 64; idx += 256) {
        int r = idx >> 6, dd = idx & 63;
        float v = 0.f;
        if (tb + r - 3 >= 0)
            v = xz[(size_t)(m0 + r - 3) * (2 * DINNER) + d0 + dd];
        s_in[r][dd] = v;
    }
    __syncthreads();

    const int dl = tid & 63;
    const int tg = tid >> 6;
    const int d = d0 + dl;
    const float4 w = *reinterpret_cast<const float4*>(&cw[d * DCONV]);
    const float bia = cb[d];
    #pragma unroll
    for (int j = 0; j < 4; ++j) {
        int tt = tg * 4 + j;
        float acc = bia;
        acc = fmaf(s_in[tt + 0][dl], w.x, acc);
        acc = fmaf(s_in[tt + 1][dl], w.y, acc);
        acc = fmaf(s_in[tt + 2][dl], w.z, acc);
        acc = fmaf(s_in[tt + 3][dl], w.w, acc);
        s_out[dl][tt] = acc * sigmoid_f(acc);
    }
    __syncthreads();

    const int dd2 = tid >> 2;
    const int tc = (tid & 3) * 4;
    float4 o;
    o.x = s_out[dd2][tc + 0]; o.y = s_out[dd2][tc + 1];
    o.z = s_out[dd2][tc + 2]; o.w = s_out[dd2][tc + 3];
    *reinterpret_cast<float4*>(&xsT[(size_t)(d0 + dd2) * MTOK + m0 + tc]) = o;
}

// dst[r][c] = src[c][r]; grid = (C/32, R/32)
__global__ __launch_bounds__(256) void transpose32(const float* __restrict__ src, int ld_src,
                                                   float* __restrict__ dst, int ld_dst)
{
    __shared__ float t[32][33];
    const int c0 = blockIdx.x * 32;
    const int r0 = blockIdx.y * 32;
    const int tx = threadIdx.x & 31;
    const int ty = threadIdx.x >> 5;
    #pragma unroll
    for (int rep = 0; rep < 4; ++rep) {
        int row = ty + rep * 8;
        t[row][tx] = src[(size_t)(c0 + row) * ld_src + r0 + tx];
    }
    __syncthreads();
    #pragma unroll
    for (int rep = 0; rep < 4; ++rep) {
        int row = ty + rep * 8;
        dst[(size_t)(r0 + row) * ld_dst + c0 + tx] = t[tx][row];
    }
}

// selective scan, time-major float4, register prefetch; y stored transposed
__global__ __launch_bounds__(256) void scan_kernel(const float* __restrict__ dtT,
                                                   const float* __restrict__ xsT,
                                                   const float* __restrict__ bcT,
                                                   const float* __restrict__ zT,
                                                   const float* __restrict__ A_log,
                                                   const float* __restrict__ Dp,
                                                   float* __restrict__ yT)
{
    const int wave = (blockIdx.x * blockDim.x + threadIdx.x) >> 6;
    const int lane = threadIdx.x & 63;
    const int s = lane & 15;
    const int di = lane >> 4;
    const int b = wave >> 9;
    const int d = ((wave & 511) << 2) + di;

    const float a = -__expf(A_log[d * DSTATE + s]);
    const float Dv = Dp[d];

    const float4* dtp = reinterpret_cast<const float4*>(dtT + (size_t)d * MTOK + b * T_LEN);
    const float4* xsp = reinterpret_cast<const float4*>(xsT + (size_t)d * MTOK + b * T_LEN);
    const float4* Bp  = reinterpret_cast<const float4*>(bcT + (size_t)s * MTOK + b * T_LEN);
    const float4* Cp  = reinterpret_cast<const float4*>(bcT + (size_t)(DSTATE + s) * MTOK + b * T_LEN);
    const float4* zp  = reinterpret_cast<const float4*>(zT + (size_t)d * MTOK + b * T_LEN);
    float4* yp = reinterpret_cast<float4*>(yT + (size_t)d * MTOK + b * T_LEN);

    float4 dt0 = dtp[0], xs0 = xsp[0], B0 = Bp[0], C0 = Cp[0], z0 = zp[0];
    float h = 0.f;

    for (int q = 0; q < T_LEN / 4; ++q) {
        const float4 dtv = dt0, xv = xs0, Bv = B0, Cv = C0, zv = z0;
        if (q < T_LEN / 4 - 1) {
            dt0 = dtp[q + 1]; xs0 = xsp[q + 1]; B0 = Bp[q + 1];
            C0 = Cp[q + 1];   z0 = zp[q + 1];
        }
        float4 yv;
        #define SCAN_STEP(c)                                                    \
        {                                                                       \
            const float dtj = dtv.c;                                            \
            const float dA = __expf(dtj * a);                                   \
            h = fmaf(dA, h, dtj * xv.c * Bv.c);                                 \
            float p = h * Cv.c;                                                 \
            p += __shfl_xor(p, 1, 64);                                          \
            p += __shfl_xor(p, 2, 64);                                          \
            p += __shfl_xor(p, 4, 64);                                          \
            p += __shfl_xor(p, 8, 64);                                          \
            yv.c = p;                                                           \
        }
        SCAN_STEP(x) SCAN_STEP(y) SCAN_STEP(z) SCAN_STEP(w)
        #undef SCAN_STEP
        if (s == 0) {
            float4 o;
            #define GATE(c) { float g = zv.c * sigmoid_f(zv.c); o.c = (yv.c + xv.c * Dv) * g; }
            GATE(x) GATE(y) GATE(z) GATE(w)
            #undef GATE
            yp[q] = o;
        }
    }
}

extern "C" void kernel_launch(void* const* d_in, const int* in_sizes, int n_in,
                              void* d_out, int out_size, void* d_ws, size_t ws_size,
                              hipStream_t stream) {
    const float* x         = (const float*)d_in[0];
    const float* in_proj_w = (const float*)d_in[1];
    const float* conv_w    = (const float*)d_in[2];
    const float* conv_b    = (const float*)d_in[3];
    const float* x_proj_w  = (const float*)d_in[4];
    const float* dt_proj_w = (const float*)d_in[5];
    const float* dt_proj_b = (const float*)d_in[6];
    const float* A_log     = (const float*)d_in[7];
    const float* D_param   = (const float*)d_in[8];
    const float* out_proj_w= (const float*)d_in[9];
    float* out = (float*)d_out;

    // ws layout (floats):
    // [0, 8M)    xz (2048 x 4096); after xz dead: dtT = [0,4M), yT = [4M,8M)
    // [8M, 12M)  xsT; after scan: yM (y in [m][d] fp32)
    // [12M, 16M) zT
    // [16M, ..)  xdbl (2048x96), bcT (32x2048)
    float* ws   = (float*)d_ws;
    const size_t M4 = (size_t)4 * 1024 * 1024;
    float* xz   = ws;
    float* dtT  = ws;
    float* yT   = ws + M4;
    float* xsT  = ws + 2 * M4;
    float* yM   = ws + 2 * M4;   // aliases xsT (xsT dead after scan)
    float* zT   = ws + 3 * M4;
    float* xdbl = ws + 4 * M4;
    float* bcT  = xdbl + (size_t)MTOK * 96;

    dim3 blk(256);

    // 1. in_proj (bf16 MFMA): xz[m][4096] = x @ in_proj_w^T
    mfma_gemm_nt<<<dim3((2 * DINNER) / 128, MTOK / 128), blk, 0, stream>>>(
        x, DMODEL, in_proj_w, DMODEL, xz, 2 * DINNER, DMODEL);

    // 2. causal conv + SiLU -> xsT[d][m]
    conv_silu_t_kernel<<<dim3(MTOK / 16, DINNER / 64), blk, 0, stream>>>(xz, conv_w, conv_b, xsT);

    // 3. zT[d][m] = xz[m][2048+d]
    transpose32<<<dim3(MTOK / 32, DINNER / 32), blk, 0, stream>>>(xz + DINNER, 2 * DINNER, zT, MTOK);

    // 4. x_proj (fp32): xdbl[m][96] = xs @ x_proj_w^T
    gemm_nt<0, 1><<<dim3(2, 32), blk, 0, stream>>>(
        xsT, MTOK, x_proj_w, DINNER, xdbl, 96, MTOK, DTRANK + 2 * DSTATE, DINNER, nullptr);

    // 5. dt_proj (fp32, transposed-out): dtT[e][m] = softplus(W_dt @ dt_in^T + b[e])
    gemm_nt<2, 0><<<dim3(32, 32), blk, 0, stream>>>(
        dt_proj_w, DTRANK, xdbl, 96, dtT, MTOK, DINNER, MTOK, DTRANK, dt_proj_b);

    // 6. bcT[0:16][m] = B^T, bcT[16:32][m] = C^T
    transpose32<<<dim3(MTOK / 32, 1), blk, 0, stream>>>(xdbl + DTRANK, 96, bcT, MTOK);

    // 7. selective scan + gated epilogue -> yT[d][m]
    scan_kernel<<<dim3(256), blk, 0, stream>>>(dtT, xsT, bcT, zT, A_log, D_param, yT);

    // 8. yM[m][d] = yT[d][m]  (into dead xsT region)
    transpose32<<<dim3(DINNER / 32, MTOK / 32), blk, 0, stream>>>(yT, MTOK, yM, DINNER);

    // 9. out_proj (bf16 MFMA): out[m][1024] = y @ out_proj_w^T
    mfma_gemm_nt<<<dim3(DMODEL / 128, MTOK / 128), blk, 0, stream>>>(
        yM, DINNER, out_proj_w, DINNER, out, DMODEL, DINNER);
}

// Round 5
// 371.365 us; speedup vs baseline: 3.9663x; 1.5353x over previous
//
#include <hip/hip_runtime.h>
#include <hip/hip_bf16.h>
#include <math.h>

#define B_SZ 2
#define T_LEN 1024
#define DMODEL 1024
#define DINNER 2048
#define DSTATE 16
#define DCONV 4
#define DTRANK 64
#define MTOK (B_SZ * T_LEN)   // 2048 tokens

typedef __bf16 bf16x4 __attribute__((ext_vector_type(4)));
typedef __bf16 bf16x8 __attribute__((ext_vector_type(8)));
typedef float  f32x4  __attribute__((ext_vector_type(4)));

__device__ __forceinline__ float sigmoid_f(float v) { return 1.f / (1.f + __expf(-v)); }

// ---------------------------------------------------------------------------
// bf16 MFMA GEMM: C[M,N] = A[M,K] * B[N,K]^T, fp32 in/out, fp32 accumulate.
// 128x128 tile, 4 waves (2x2 of 64x64), K_STEP=64, v_mfma_f32_16x16x32_bf16.
// ---------------------------------------------------------------------------
#define LDK 72

__global__ __launch_bounds__(256) void mfma_gemm_nt(const float* __restrict__ A, int lda,
                                                    const float* __restrict__ Bm, int ldb,
                                                    float* __restrict__ C, int ldc,
                                                    int K)
{
    __shared__ __bf16 As[128 * LDK];
    __shared__ __bf16 Bs[128 * LDK];
    const int tid  = threadIdx.x;
    const int lane = tid & 63;
    const int w    = tid >> 6;
    const int wr   = w >> 1, wc = w & 1;
    const int m0   = blockIdx.y * 128, n0 = blockIdx.x * 128;

    const int srow  = tid >> 1;
    const int skoff = (tid & 1) * 32;

    f32x4 acc[4][4];
    #pragma unroll
    for (int i = 0; i < 4; ++i)
        #pragma unroll
        for (int j = 0; j < 4; ++j) {
            f32x4 z = {0.f, 0.f, 0.f, 0.f};
            acc[i][j] = z;
        }

    const int fr = lane & 15;
    const int kq = (lane >> 4) * 8;

    for (int k0 = 0; k0 < K; k0 += 64) {
        const float* gA = A  + (size_t)(m0 + srow) * lda + k0 + skoff;
        const float* gB = Bm + (size_t)(n0 + srow) * ldb + k0 + skoff;
        __bf16* sA = As + srow * LDK + skoff;
        __bf16* sB = Bs + srow * LDK + skoff;
        #pragma unroll
        for (int p = 0; p < 8; ++p) {
            float4 va = *reinterpret_cast<const float4*>(gA + 4 * p);
            bf16x4 ba = {(__bf16)va.x, (__bf16)va.y, (__bf16)va.z, (__bf16)va.w};
            *reinterpret_cast<bf16x4*>(sA + 4 * p) = ba;
            float4 vb = *reinterpret_cast<const float4*>(gB + 4 * p);
            bf16x4 bb = {(__bf16)vb.x, (__bf16)vb.y, (__bf16)vb.z, (__bf16)vb.w};
            *reinterpret_cast<bf16x4*>(sB + 4 * p) = bb;
        }
        __syncthreads();

        bf16x8 af[4][2], bfr[4][2];
        #pragma unroll
        for (int i = 0; i < 4; ++i) {
            const __bf16* pa = As + (wr * 64 + i * 16 + fr) * LDK + kq;
            af[i][0] = *reinterpret_cast<const bf16x8*>(pa);
            af[i][1] = *reinterpret_cast<const bf16x8*>(pa + 32);
        }
        #pragma unroll
        for (int j = 0; j < 4; ++j) {
            const __bf16* pb = Bs + (wc * 64 + j * 16 + fr) * LDK + kq;
            bfr[j][0] = *reinterpret_cast<const bf16x8*>(pb);
            bfr[j][1] = *reinterpret_cast<const bf16x8*>(pb + 32);
        }
        #pragma unroll
        for (int i = 0; i < 4; ++i)
            #pragma unroll
            for (int j = 0; j < 4; ++j) {
                acc[i][j] = __builtin_amdgcn_mfma_f32_16x16x32_bf16(af[i][0], bfr[j][0], acc[i][j], 0, 0, 0);
                acc[i][j] = __builtin_amdgcn_mfma_f32_16x16x32_bf16(af[i][1], bfr[j][1], acc[i][j], 0, 0, 0);
            }
        __syncthreads();
    }

    const int crow = (lane >> 4) * 4;
    const int ccol = lane & 15;
    #pragma unroll
    for (int i = 0; i < 4; ++i)
        #pragma unroll
        for (int j = 0; j < 4; ++j) {
            float* cp = C + (size_t)(m0 + wr * 64 + i * 16 + crow) * ldc
                          + n0 + wc * 64 + j * 16 + ccol;
            cp[0 * ldc] = acc[i][j][0];
            cp[1 * ldc] = acc[i][j][1];
            cp[2 * ldc] = acc[i][j][2];
            cp[3 * ldc] = acc[i][j][3];
        }
}

// ---------------------------------------------------------------------------
// fp32 vector GEMM (dt_proj): C[M,N] = A[M,K] * B[N,K]^T, EPI=softplus(+bias[m])
// ---------------------------------------------------------------------------
template<int EPI, int TA>
__global__ __launch_bounds__(256) void gemm_nt(const float* __restrict__ A, int lda,
                                               const float* __restrict__ Bm, int ldb,
                                               float* __restrict__ C, int ldc,
                                               int M, int N, int K,
                                               const float* __restrict__ bias)
{
    __shared__ float As[16][68];
    __shared__ float Bs[16][68];
    const int tx = threadIdx.x & 15;
    const int ty = threadIdx.x >> 4;
    const int m0 = blockIdx.y * 64;
    const int n0 = blockIdx.x * 64;
    const int lr = threadIdx.x >> 2;
    const int lc = (threadIdx.x & 3) * 4;
    const int kk16 = threadIdx.x >> 4;
    const int mc16 = (threadIdx.x & 15) * 4;

    float acc[4][4] = {};

    for (int k0 = 0; k0 < K; k0 += 16) {
        if (TA) {
            float4 v = *reinterpret_cast<const float4*>(&A[(size_t)(k0 + kk16) * lda + m0 + mc16]);
            As[kk16][mc16 + 0] = v.x; As[kk16][mc16 + 1] = v.y;
            As[kk16][mc16 + 2] = v.z; As[kk16][mc16 + 3] = v.w;
        } else {
            int m = m0 + lr;
            float4 v = make_float4(0.f, 0.f, 0.f, 0.f);
            if (m < M) v = *reinterpret_cast<const float4*>(&A[(size_t)m * lda + k0 + lc]);
            As[lc + 0][lr] = v.x; As[lc + 1][lr] = v.y;
            As[lc + 2][lr] = v.z; As[lc + 3][lr] = v.w;
        }
        {
            int n = n0 + lr;
            float4 v = make_float4(0.f, 0.f, 0.f, 0.f);
            if (n < N) v = *reinterpret_cast<const float4*>(&Bm[(size_t)n * ldb + k0 + lc]);
            Bs[lc + 0][lr] = v.x; Bs[lc + 1][lr] = v.y;
            Bs[lc + 2][lr] = v.z; Bs[lc + 3][lr] = v.w;
        }
        __syncthreads();
        #pragma unroll
        for (int kk = 0; kk < 16; ++kk) {
            float av[4], bv[4];
            #pragma unroll
            for (int i = 0; i < 4; ++i) av[i] = As[kk][ty + 16 * i];
            #pragma unroll
            for (int j = 0; j < 4; ++j) bv[j] = Bs[kk][tx + 16 * j];
            #pragma unroll
            for (int i = 0; i < 4; ++i)
                #pragma unroll
                for (int j = 0; j < 4; ++j)
                    acc[i][j] = fmaf(av[i], bv[j], acc[i][j]);
        }
        __syncthreads();
    }

    #pragma unroll
    for (int i = 0; i < 4; ++i) {
        int m = m0 + ty + 16 * i;
        if (m >= M) continue;
        float rb = (EPI == 2) ? bias[m] : 0.f;
        #pragma unroll
        for (int j = 0; j < 4; ++j) {
            int n = n0 + tx + 16 * j;
            if (n >= N) continue;
            float v = acc[i][j];
            if (EPI == 2) {
                v += rb;
                v = (v > 20.f) ? v : log1pf(__expf(v));
            }
            C[(size_t)m * ldc + n] = v;
        }
    }
}

// ---------------------------------------------------------------------------
// x_proj split-K: xdbl_partial[kz][m][96] = xsT-slice^T @ W_x^T over k-chunk kz
// ---------------------------------------------------------------------------
#define XP_KS 16
#define XP_KC (DINNER / XP_KS)   // 128

__global__ __launch_bounds__(256) void gemm_xproj_splitk(const float* __restrict__ xsT,
                                                         const float* __restrict__ W,
                                                         float* __restrict__ pbuf)
{
    __shared__ float As[16][68];
    __shared__ float Bs[16][68];
    const int tx = threadIdx.x & 15;
    const int ty = threadIdx.x >> 4;
    const int n0 = blockIdx.x * 64;
    const int m0 = blockIdx.y * 64;
    const int kz = blockIdx.z;
    const int lr = threadIdx.x >> 2;
    const int lc = (threadIdx.x & 3) * 4;
    const int kk16 = threadIdx.x >> 4;
    const int mc16 = (threadIdx.x & 15) * 4;

    float acc[4][4] = {};

    for (int k0 = kz * XP_KC; k0 < (kz + 1) * XP_KC; k0 += 16) {
        {
            float4 v = *reinterpret_cast<const float4*>(&xsT[(size_t)(k0 + kk16) * MTOK + m0 + mc16]);
            As[kk16][mc16 + 0] = v.x; As[kk16][mc16 + 1] = v.y;
            As[kk16][mc16 + 2] = v.z; As[kk16][mc16 + 3] = v.w;
        }
        {
            int n = n0 + lr;
            float4 v = make_float4(0.f, 0.f, 0.f, 0.f);
            if (n < DTRANK + 2 * DSTATE)
                v = *reinterpret_cast<const float4*>(&W[(size_t)n * DINNER + k0 + lc]);
            Bs[lc + 0][lr] = v.x; Bs[lc + 1][lr] = v.y;
            Bs[lc + 2][lr] = v.z; Bs[lc + 3][lr] = v.w;
        }
        __syncthreads();
        #pragma unroll
        for (int kk = 0; kk < 16; ++kk) {
            float av[4], bv[4];
            #pragma unroll
            for (int i = 0; i < 4; ++i) av[i] = As[kk][ty + 16 * i];
            #pragma unroll
            for (int j = 0; j < 4; ++j) bv[j] = Bs[kk][tx + 16 * j];
            #pragma unroll
            for (int i = 0; i < 4; ++i)
                #pragma unroll
                for (int j = 0; j < 4; ++j)
                    acc[i][j] = fmaf(av[i], bv[j], acc[i][j]);
        }
        __syncthreads();
    }

    float* pc = pbuf + (size_t)kz * MTOK * 96;
    #pragma unroll
    for (int i = 0; i < 4; ++i) {
        int m = m0 + ty + 16 * i;
        #pragma unroll
        for (int j = 0; j < 4; ++j) {
            int n = n0 + tx + 16 * j;
            if (n < 96) pc[(size_t)m * 96 + n] = acc[i][j];
        }
    }
}

// xdbl[m][e] = sum_kz pbuf[kz][m][e]; float4 over MTOK*96/4 = 49152 elements
__global__ __launch_bounds__(256) void reduce_xproj(const float* __restrict__ pbuf,
                                                    float* __restrict__ xdbl)
{
    const int idx = blockIdx.x * blockDim.x + threadIdx.x;
    const float4* p = reinterpret_cast<const float4*>(pbuf) + idx;
    float4 s = p[0];
    #pragma unroll
    for (int z = 1; z < XP_KS; ++z) {
        float4 v = p[(size_t)z * (MTOK * 96 / 4)];
        s.x += v.x; s.y += v.y; s.z += v.z; s.w += v.w;
    }
    reinterpret_cast<float4*>(xdbl)[idx] = s;
}

// causal depthwise conv (k=4, left pad 3) + bias + SiLU, output TRANSPOSED
__global__ __launch_bounds__(256) void conv_silu_t_kernel(const float* __restrict__ xz,
                                                          const float* __restrict__ cw,
                                                          const float* __restrict__ cb,
                                                          float* __restrict__ xsT)
{
    __shared__ float s_in[19][64];
    __shared__ float s_out[64][17];
    const int m0 = blockIdx.x * 16;
    const int d0 = blockIdx.y * 64;
    const int tid = threadIdx.x;
    const int tb = m0 & (T_LEN - 1);

    for (int idx = tid; idx < 19 * 64; idx += 256) {
        int r = idx >> 6, dd = idx & 63;
        float v = 0.f;
        if (tb + r - 3 >= 0)
            v = xz[(size_t)(m0 + r - 3) * (2 * DINNER) + d0 + dd];
        s_in[r][dd] = v;
    }
    __syncthreads();

    const int dl = tid & 63;
    const int tg = tid >> 6;
    const int d = d0 + dl;
    const float4 w = *reinterpret_cast<const float4*>(&cw[d * DCONV]);
    const float bia = cb[d];
    #pragma unroll
    for (int j = 0; j < 4; ++j) {
        int tt = tg * 4 + j;
        float acc = bia;
        acc = fmaf(s_in[tt + 0][dl], w.x, acc);
        acc = fmaf(s_in[tt + 1][dl], w.y, acc);
        acc = fmaf(s_in[tt + 2][dl], w.z, acc);
        acc = fmaf(s_in[tt + 3][dl], w.w, acc);
        s_out[dl][tt] = acc * sigmoid_f(acc);
    }
    __syncthreads();

    const int dd2 = tid >> 2;
    const int tc = (tid & 3) * 4;
    float4 o;
    o.x = s_out[dd2][tc + 0]; o.y = s_out[dd2][tc + 1];
    o.z = s_out[dd2][tc + 2]; o.w = s_out[dd2][tc + 3];
    *reinterpret_cast<float4*>(&xsT[(size_t)(d0 + dd2) * MTOK + m0 + tc]) = o;
}

// dst[r][c] = src[c][r]; grid = (C/32, R/32)  (used for bcT)
__global__ __launch_bounds__(256) void transpose32(const float* __restrict__ src, int ld_src,
                                                   float* __restrict__ dst, int ld_dst)
{
    __shared__ float t[32][33];
    const int c0 = blockIdx.x * 32;
    const int r0 = blockIdx.y * 32;
    const int tx = threadIdx.x & 31;
    const int ty = threadIdx.x >> 5;
    #pragma unroll
    for (int rep = 0; rep < 4; ++rep) {
        int row = ty + rep * 8;
        t[row][tx] = src[(size_t)(c0 + row) * ld_src + r0 + tx];
    }
    __syncthreads();
    #pragma unroll
    for (int rep = 0; rep < 4; ++rep) {
        int row = ty + rep * 8;
        dst[(size_t)(r0 + row) * ld_dst + c0 + tx] = t[tx][row];
    }
}

// yM[m][d] = yT[d][m] * silu(z[m][d]);  yT ld 4096 (lives in xz x-cols),
// z read from xz z-cols (m*4096 + 2048 + d).
__global__ __launch_bounds__(256) void gate_transpose(const float* __restrict__ yT,
                                                      const float* __restrict__ xz,
                                                      float* __restrict__ yM)
{
    __shared__ float t[32][33];
    const int d0 = blockIdx.x * 32;
    const int m0 = blockIdx.y * 32;
    const int tx = threadIdx.x & 31;
    const int ty = threadIdx.x >> 5;
    #pragma unroll
    for (int rep = 0; rep < 4; ++rep) {
        int row = ty + rep * 8;
        t[row][tx] = yT[(size_t)(d0 + row) * 4096 + m0 + tx];
    }
    __syncthreads();
    #pragma unroll
    for (int rep = 0; rep < 4; ++rep) {
        int row = ty + rep * 8;
        int m = m0 + row;
        float zv = xz[(size_t)m * 4096 + 2048 + d0 + tx];
        float g = zv * sigmoid_f(zv);
        yM[(size_t)m * DINNER + d0 + tx] = t[tx][row] * g;
    }
}

// selective scan, time-major float4, register prefetch; writes yT (ld 4096, no gate)
__global__ __launch_bounds__(256) void scan_kernel(const float* __restrict__ dtT,
                                                   const float* __restrict__ xsT,
                                                   const float* __restrict__ bcT,
                                                   const float* __restrict__ A_log,
                                                   const float* __restrict__ Dp,
                                                   float* __restrict__ yT)
{
    const int wave = (blockIdx.x * blockDim.x + threadIdx.x) >> 6;
    const int lane = threadIdx.x & 63;
    const int s = lane & 15;
    const int di = lane >> 4;
    const int b = wave >> 9;
    const int d = ((wave & 511) << 2) + di;

    const float a = -__expf(A_log[d * DSTATE + s]);
    const float Dv = Dp[d];

    const float4* dtp = reinterpret_cast<const float4*>(dtT + (size_t)d * MTOK + b * T_LEN);
    const float4* xsp = reinterpret_cast<const float4*>(xsT + (size_t)d * MTOK + b * T_LEN);
    const float4* Bp  = reinterpret_cast<const float4*>(bcT + (size_t)s * MTOK + b * T_LEN);
    const float4* Cp  = reinterpret_cast<const float4*>(bcT + (size_t)(DSTATE + s) * MTOK + b * T_LEN);
    float4* yp = reinterpret_cast<float4*>(yT + (size_t)d * 4096 + b * T_LEN);

    float4 dt0 = dtp[0], xs0 = xsp[0], B0 = Bp[0], C0 = Cp[0];
    float h = 0.f;

    for (int q = 0; q < T_LEN / 4; ++q) {
        const float4 dtv = dt0, xv = xs0, Bv = B0, Cv = C0;
        if (q < T_LEN / 4 - 1) {
            dt0 = dtp[q + 1]; xs0 = xsp[q + 1]; B0 = Bp[q + 1]; C0 = Cp[q + 1];
        }
        float4 yv;
        #define SCAN_STEP(c)                                                    \
        {                                                                       \
            const float dtj = dtv.c;                                            \
            const float dA = __expf(dtj * a);                                   \
            h = fmaf(dA, h, dtj * xv.c * Bv.c);                                 \
            float p = h * Cv.c;                                                 \
            p += __shfl_xor(p, 1, 64);                                          \
            p += __shfl_xor(p, 2, 64);                                          \
            p += __shfl_xor(p, 4, 64);                                          \
            p += __shfl_xor(p, 8, 64);                                          \
            yv.c = p;                                                           \
        }
        SCAN_STEP(x) SCAN_STEP(y) SCAN_STEP(z) SCAN_STEP(w)
        #undef SCAN_STEP
        if (s == 0) {
            float4 o;
            o.x = yv.x + xv.x * Dv; o.y = yv.y + xv.y * Dv;
            o.z = yv.z + xv.z * Dv; o.w = yv.w + xv.w * Dv;
            yp[q] = o;
        }
    }
}

extern "C" void kernel_launch(void* const* d_in, const int* in_sizes, int n_in,
                              void* d_out, int out_size, void* d_ws, size_t ws_size,
                              hipStream_t stream) {
    const float* x         = (const float*)d_in[0];
    const float* in_proj_w = (const float*)d_in[1];
    const float* conv_w    = (const float*)d_in[2];
    const float* conv_b    = (const float*)d_in[3];
    const float* x_proj_w  = (const float*)d_in[4];
    const float* dt_proj_w = (const float*)d_in[5];
    const float* dt_proj_b = (const float*)d_in[6];
    const float* A_log     = (const float*)d_in[7];
    const float* D_param   = (const float*)d_in[8];
    const float* out_proj_w= (const float*)d_in[9];
    float* out = (float*)d_out;

    // ws (floats):
    // [0, 8M)    xz [2048][4096]; after conv, x-cols (0..2047) reused as yT (ld 4096);
    //            z-cols (2048..4095) stay live until gate_transpose.
    // [8M, 12M)  xsT; after scan reused as yM.
    // [12M,16M)  pbuf (3.07M, dead after reduce) then dtT (4M, written after).
    // [16M, ..)  xdbl (2048x96), bcT (32x2048).
    float* ws   = (float*)d_ws;
    const size_t M4 = (size_t)4 * 1024 * 1024;
    float* xz   = ws;
    float* yT   = ws;            // x-cols of xz, ld 4096
    float* xsT  = ws + 2 * M4;
    float* yM   = ws + 2 * M4;
    float* pbuf = ws + 3 * M4;
    float* dtT  = ws + 3 * M4;
    float* xdbl = ws + 4 * M4;
    float* bcT  = xdbl + (size_t)MTOK * 96;

    dim3 blk(256);

    // 1. in_proj (bf16 MFMA): xz[m][4096] = x @ in_proj_w^T
    mfma_gemm_nt<<<dim3((2 * DINNER) / 128, MTOK / 128), blk, 0, stream>>>(
        x, DMODEL, in_proj_w, DMODEL, xz, 2 * DINNER, DMODEL);

    // 2. causal conv + SiLU -> xsT[d][m]
    conv_silu_t_kernel<<<dim3(MTOK / 16, DINNER / 64), blk, 0, stream>>>(xz, conv_w, conv_b, xsT);

    // 3. x_proj split-K (fp32): pbuf[kz][m][96]
    gemm_xproj_splitk<<<dim3(2, MTOK / 64, XP_KS), blk, 0, stream>>>(xsT, x_proj_w, pbuf);

    // 4. reduce partials -> xdbl[m][96]
    reduce_xproj<<<dim3(MTOK * 96 / 4 / 256), blk, 0, stream>>>(pbuf, xdbl);

    // 5. dt_proj (fp32, transposed-out): dtT[e][m] = softplus(W_dt @ dt_in^T + b[e])
    gemm_nt<2, 0><<<dim3(32, 32), blk, 0, stream>>>(
        dt_proj_w, DTRANK, xdbl, 96, dtT, MTOK, DINNER, MTOK, DTRANK, dt_proj_b);

    // 6. bcT[0:16][m] = B^T, bcT[16:32][m] = C^T
    transpose32<<<dim3(MTOK / 32, 1), blk, 0, stream>>>(xdbl + DTRANK, 96, bcT, MTOK);

    // 7. selective scan -> yT[d][m] (ld 4096, in dead xz x-cols)
    scan_kernel<<<dim3(256), blk, 0, stream>>>(dtT, xsT, bcT, A_log, D_param, yT);

    // 8. gate + transpose: yM[m][d] = yT[d][m] * silu(z[m][d])
    gate_transpose<<<dim3(DINNER / 32, MTOK / 32), blk, 0, stream>>>(yT, xz, yM);

    // 9. out_proj (bf16 MFMA): out[m][1024] = y @ out_proj_w^T
    mfma_gemm_nt<<<dim3(DMODEL / 128, MTOK / 128), blk, 0, stream>>>(
        yM, DINNER, out_proj_w, DINNER, out, DMODEL, DINNER);
}